// Round 1
// baseline (809.794 us; speedup 1.0000x reference)
//
#include <hip/hip_runtime.h>

typedef _Float16 f16;
typedef __attribute__((ext_vector_type(8))) _Float16 f16x8;
typedef __attribute__((ext_vector_type(4))) float f32x4;

#define B_ 2
#define S_ 2048
#define DMODEL 768
#define H_ 12
#define HS 64
#define NB_ 16
#define QKV_LD 2304   // q,k,v concatenated columns

// ---------------- cast fp32 -> fp16 (optionally scaled) ----------------
__global__ __launch_bounds__(256) void cast_f16_kernel(const float* __restrict__ in,
                                                       f16* __restrict__ out,
                                                       int n4, float scale) {
    int i = blockIdx.x * 256 + threadIdx.x;
    if (i >= n4) return;
    float4 v = reinterpret_cast<const float4*>(in)[i];
    union { f16 h[4]; unsigned long long u; } o;
    o.h[0] = (f16)(v.x * scale);
    o.h[1] = (f16)(v.y * scale);
    o.h[2] = (f16)(v.z * scale);
    o.h[3] = (f16)(v.w * scale);
    reinterpret_cast<unsigned long long*>(out)[i] = o.u;
}

// ---------------- relative-position bias table: tab[h][d], d = k-q+2047 ----------------
__global__ __launch_bounds__(256) void bias_table_kernel(const float* __restrict__ bw,
                                                         const float* __restrict__ bf,
                                                         float* __restrict__ tab) {
    int idx = blockIdx.x * 256 + threadIdx.x;
    if (idx >= H_ * 4095) return;
    int h = idx / 4095, d = idx % 4095;
    int rel = d - 2047;
    rel = min(1000, max(-1000, rel));
    int r = rel + 1000;
    float s = 0.f;
#pragma unroll
    for (int t = 0; t < NB_; ++t) s += bf[r * NB_ + t] * bw[h * NB_ + t];
    tab[h * 4095 + d] = s;
}

// ---------------- NT GEMM: C[M][N] = alpha * A[M][K] @ B[N][K]^T ----------------
// 128x128 tile, 4 waves (2x2), each wave 64x64 via 4x4 mfma_f32_16x16x32_f16
template <typename OutT>
__global__ __launch_bounds__(256) void gemm_nt(const f16* __restrict__ A,
                                               const f16* __restrict__ Bm,
                                               OutT* __restrict__ C,
                                               int M, int N, int K, float alpha) {
    __shared__ __align__(16) f16 As[128][32];
    __shared__ __align__(16) f16 Bs[128][32];
    const int tiles_n = N >> 7;
    int tm = blockIdx.x / tiles_n, tn = blockIdx.x % tiles_n;
    int m0 = tm << 7, n0 = tn << 7;
    int t = threadIdx.x;
    int w = t >> 6, l = t & 63;
    int wr = w >> 1, wc = w & 1;
    int fr = l & 15, fc = (l >> 4) << 3;
    f32x4 acc[4][4] = {};

    for (int k0 = 0; k0 < K; k0 += 32) {
#pragma unroll
        for (int uu = 0; uu < 2; ++uu) {
            int u = t + uu * 256;          // 512 units: row=u>>2, cgroup=u&3
            int row = u >> 2, c = (u & 3) << 3;
            *reinterpret_cast<f16x8*>(&As[row][c]) =
                *reinterpret_cast<const f16x8*>(&A[(size_t)(m0 + row) * K + k0 + c]);
            *reinterpret_cast<f16x8*>(&Bs[row][c]) =
                *reinterpret_cast<const f16x8*>(&Bm[(size_t)(n0 + row) * K + k0 + c]);
        }
        __syncthreads();
        f16x8 af[4], bfv[4];
#pragma unroll
        for (int m = 0; m < 4; ++m)
            af[m] = *reinterpret_cast<const f16x8*>(&As[wr * 64 + m * 16 + fr][fc]);
#pragma unroll
        for (int n = 0; n < 4; ++n)
            bfv[n] = *reinterpret_cast<const f16x8*>(&Bs[wc * 64 + n * 16 + fr][fc]);
#pragma unroll
        for (int m = 0; m < 4; ++m)
#pragma unroll
            for (int n = 0; n < 4; ++n)
                acc[m][n] = __builtin_amdgcn_mfma_f32_16x16x32_f16(af[m], bfv[n], acc[m][n], 0, 0, 0);
        __syncthreads();
    }
    // epilogue: D layout col=lane&15, row=(lane>>4)*4+j
    int cc = l & 15, cr = (l >> 4) << 2;
#pragma unroll
    for (int m = 0; m < 4; ++m)
#pragma unroll
        for (int n = 0; n < 4; ++n)
#pragma unroll
            for (int j = 0; j < 4; ++j) {
                int rg = m0 + wr * 64 + m * 16 + cr + j;
                int cg = n0 + wc * 64 + n * 16 + cc;
                C[(size_t)rg * N + cg] = (OutT)(acc[m][n][j] * alpha);
            }
}

// ---------------- attention: per (b,h,16 q-rows): scores->softmax->attn write->PV ----------------
__global__ __launch_bounds__(256) void attn_kernel(const f16* __restrict__ qp,
                                                   const f16* __restrict__ kp,
                                                   const f16* __restrict__ vp,
                                                   const float* __restrict__ biasTab,
                                                   float* __restrict__ attn_out,
                                                   f16* __restrict__ ctx_out) {
    __shared__ __align__(16) float sc[16][2048];   // 128 KB, columns XOR-swizzled by row
    __shared__ __align__(16) f16 Ks[64][72];       // padded rows (144 B = 36 words)
    __shared__ __align__(16) f16 VsT[64][72];      // transposed V tile, padded
    __shared__ float linv_s[16];

    int blk = blockIdx.x;
    int qt = blk & 127;            // S/16 = 128 q-tiles
    int bh = blk >> 7;
    int h = bh % H_;
    int b = bh / H_;
    int q0 = qt << 4;

    int t = threadIdx.x;
    int w = t >> 6, l = t & 63;
    int fr = l & 15, fc = (l >> 4) << 3;

    const size_t rowbase = (size_t)b * S_ * QKV_LD + (size_t)h * HS;

    // Q fragments held for whole kernel (q pre-scaled by 1/8 in projection)
    f16x8 qf0, qf1;
    {
        const f16* qrow = qp + rowbase + (size_t)(q0 + fr) * QKV_LD;
        qf0 = *reinterpret_cast<const f16x8*>(qrow + fc);
        qf1 = *reinterpret_cast<const f16x8*>(qrow + 32 + fc);
    }

    // ---- QK^T over all k, scores -> LDS ----
    for (int kb0 = 0; kb0 < S_; kb0 += 64) {
        {
            int row = t >> 3, c = (t & 7) << 3;
            *reinterpret_cast<f16x8*>(&Ks[row][c]) =
                *reinterpret_cast<const f16x8*>(kp + rowbase + (size_t)(kb0 + row) * QKV_LD + c);
            row += 32;
            *reinterpret_cast<f16x8*>(&Ks[row][c]) =
                *reinterpret_cast<const f16x8*>(kp + rowbase + (size_t)(kb0 + row) * QKV_LD + c);
        }
        __syncthreads();
        f16x8 b0 = *reinterpret_cast<const f16x8*>(&Ks[w * 16 + fr][fc]);
        f16x8 b1 = *reinterpret_cast<const f16x8*>(&Ks[w * 16 + fr][32 + fc]);
        f32x4 s = {};
        s = __builtin_amdgcn_mfma_f32_16x16x32_f16(qf0, b0, s, 0, 0, 0);
        s = __builtin_amdgcn_mfma_f32_16x16x32_f16(qf1, b1, s, 0, 0, 0);
        int kk = kb0 + w * 16 + fr;
        int qrb = (l >> 4) << 2;
        const float* btab = biasTab + h * 4095 + 2047 - q0 + kk;  // index d = kk-(q0+qr)+2047 -> btab[-qr]
#pragma unroll
        for (int j = 0; j < 4; ++j) {
            int qr = qrb + j;
            sc[qr][kk ^ ((qr & 7) << 3)] = s[j] + btab[-qr];
        }
        __syncthreads();
    }

    // ---- exact softmax: 16 threads per row ----
    {
        int r = t >> 4, jj = t & 15;
        int swz = (r & 7) << 3;
        float mx = -3.0e38f;
        for (int i = 0; i < 128; ++i)
            mx = fmaxf(mx, sc[r][(jj + (i << 4)) ^ swz]);
        mx = fmaxf(mx, __shfl_xor(mx, 1));
        mx = fmaxf(mx, __shfl_xor(mx, 2));
        mx = fmaxf(mx, __shfl_xor(mx, 4));
        mx = fmaxf(mx, __shfl_xor(mx, 8));
        float sum = 0.f;
        for (int i = 0; i < 128; ++i) {
            int idx = (jj + (i << 4)) ^ swz;
            float p = __expf(sc[r][idx] - mx);
            sc[r][idx] = p;
            sum += p;
        }
        sum += __shfl_xor(sum, 1);
        sum += __shfl_xor(sum, 2);
        sum += __shfl_xor(sum, 4);
        sum += __shfl_xor(sum, 8);
        if (jj == 0) linv_s[r] = 1.0f / sum;
    }
    __syncthreads();

    // ---- write normalized attn (coalesced float4) ----
    {
        float* aout = attn_out + (((size_t)b * H_ + h) * S_ + q0) * S_;
        for (int i = t; i < 16 * 512; i += 256) {
            int qrow = i >> 9;
            int c4 = (i & 511) << 2;
            float li = linv_s[qrow];
            int swz = (qrow & 7) << 3;
            float4 pv = *reinterpret_cast<const float4*>(&sc[qrow][c4 ^ swz]);
            float4 o;
            o.x = pv.x * li; o.y = pv.y * li; o.z = pv.z * li; o.w = pv.w * li;
            *reinterpret_cast<float4*>(aout + (size_t)qrow * S_ + c4) = o;
        }
    }

    // ---- PV: out[16q][64v], wave w owns v-range [w*16, w*16+16) ----
    f32x4 oacc = {};
    for (int kb0 = 0; kb0 < S_; kb0 += 64) {
        {   // stage V transposed: VsT[v][c] = V[kb0+c][v]
            int c = t >> 2, v0 = (t & 3) << 4;
            const f16* src = vp + rowbase + (size_t)(kb0 + c) * QKV_LD + v0;
            __align__(16) f16 tmp[16];
            *reinterpret_cast<f16x8*>(tmp)     = *reinterpret_cast<const f16x8*>(src);
            *reinterpret_cast<f16x8*>(tmp + 8) = *reinterpret_cast<const f16x8*>(src + 8);
#pragma unroll
            for (int i2 = 0; i2 < 16; ++i2) VsT[v0 + i2][c] = tmp[i2];
        }
        __syncthreads();
#pragma unroll
        for (int kc = 0; kc < 2; ++kc) {
            int cbase = kb0 + kc * 32 + fc;
            int swz = (fr & 7) << 3;
            const float* ps = &sc[fr][cbase ^ swz];   // 8 consecutive logical cols
            f16x8 pa;
#pragma unroll
            for (int i2 = 0; i2 < 8; ++i2) pa[i2] = (f16)ps[i2];
            f16x8 vf = *reinterpret_cast<const f16x8*>(&VsT[w * 16 + fr][kc * 32 + fc]);
            oacc = __builtin_amdgcn_mfma_f32_16x16x32_f16(pa, vf, oacc, 0, 0, 0);
        }
        __syncthreads();
    }
    {
        int cc = fr, cr = (l >> 4) << 2;
        f16* crow = ctx_out + ((size_t)b * S_ + q0) * DMODEL + h * HS + w * 16 + cc;
#pragma unroll
        for (int j = 0; j < 4; ++j) {
            int q = cr + j;
            crow[(size_t)q * DMODEL] = (f16)(oacc[j] * linv_s[q]);
        }
    }
}

// ---------------- launch ----------------
extern "C" void kernel_launch(void* const* d_in, const int* in_sizes, int n_in,
                              void* d_out, int out_size, void* d_ws, size_t ws_size,
                              hipStream_t stream) {
    const float* x     = (const float*)d_in[0];
    const float* Wq    = (const float*)d_in[1];
    const float* Wk    = (const float*)d_in[2];
    const float* Wv    = (const float*)d_in[3];
    const float* Wo    = (const float*)d_in[4];
    const float* bw    = (const float*)d_in[5];
    const float* bfeat = (const float*)d_in[6];

    char* ws = (char*)d_ws;
    f16*   xb      = (f16*)(ws + 0);           // 4096x768      6,291,456 B
    f16*   qkv     = (f16*)(ws + 6291456);     // 4096x2304    18,874,368 B
    f16*   ctx     = (f16*)(ws + 25165824);    // 4096x768      6,291,456 B
    f16*   wqkv16  = (f16*)(ws + 31457280);    // 2304x768      3,538,944 B
    f16*   wo16    = (f16*)(ws + 34996224);    // 768x768       1,179,648 B
    float* biasTab = (float*)(ws + 36175872);  // 12x4095         196,560 B

    float* out0 = (float*)d_out;
    float* attn = out0 + (size_t)B_ * S_ * DMODEL;  // + 3,145,728

    // casts (fold 1/sqrt(64) into Wq)
    cast_f16_kernel<<<3072, 256, 0, stream>>>(x, xb, 786432, 1.0f);
    cast_f16_kernel<<<576, 256, 0, stream>>>(Wq, wqkv16 + 0,        147456, 0.125f);
    cast_f16_kernel<<<576, 256, 0, stream>>>(Wk, wqkv16 + 589824,   147456, 1.0f);
    cast_f16_kernel<<<576, 256, 0, stream>>>(Wv, wqkv16 + 1179648,  147456, 1.0f);
    cast_f16_kernel<<<576, 256, 0, stream>>>(Wo, wo16,              147456, 1.0f);
    bias_table_kernel<<<192, 256, 0, stream>>>(bw, bfeat, biasTab);

    // fused QKV projection: [4096x768] @ [2304x768]^T
    gemm_nt<f16><<<32 * 18, 256, 0, stream>>>(xb, wqkv16, qkv, 4096, QKV_LD, 768, 1.0f);

    // attention: q,k,v are column slices of qkv with row stride 2304
    attn_kernel<<<B_ * H_ * (S_ / 16), 256, 0, stream>>>(
        qkv + 0, qkv + 768, qkv + 1536, biasTab, attn, ctx);

    // output projection -> fp32 d_out
    gemm_nt<float><<<32 * 6, 256, 0, stream>>>(ctx, wo16, out0, 4096, DMODEL, 768, 1.0f);
}

// Round 2
// 288.346 us; speedup vs baseline: 2.8084x; 2.8084x over previous
//
#include <hip/hip_runtime.h>

typedef _Float16 f16;
typedef __attribute__((ext_vector_type(8))) _Float16 f16x8;
typedef __attribute__((ext_vector_type(4))) float f32x4;

#define B_ 2
#define S_ 2048
#define DMODEL 768
#define H_ 12
#define HS 64
#define NB_ 16
#define QKV_LD 2304   // q,k,v concatenated columns

// ---------------- cast fp32 -> fp16 (optionally scaled) ----------------
__global__ __launch_bounds__(256) void cast_f16_kernel(const float* __restrict__ in,
                                                       f16* __restrict__ out,
                                                       int n4, float scale) {
    int i = blockIdx.x * 256 + threadIdx.x;
    if (i >= n4) return;
    float4 v = reinterpret_cast<const float4*>(in)[i];
    union { f16 h[4]; unsigned long long u; } o;
    o.h[0] = (f16)(v.x * scale);
    o.h[1] = (f16)(v.y * scale);
    o.h[2] = (f16)(v.z * scale);
    o.h[3] = (f16)(v.w * scale);
    reinterpret_cast<unsigned long long*>(out)[i] = o.u;
}

// ---------------- relative-position bias table: tab[h][d], d = k-q+2047 ----------------
__global__ __launch_bounds__(256) void bias_table_kernel(const float* __restrict__ bw,
                                                         const float* __restrict__ bf,
                                                         float* __restrict__ tab) {
    int idx = blockIdx.x * 256 + threadIdx.x;
    if (idx >= H_ * 4095) return;
    int h = idx / 4095, d = idx % 4095;
    int rel = d - 2047;
    rel = min(1000, max(-1000, rel));
    int r = rel + 1000;
    float s = 0.f;
#pragma unroll
    for (int t = 0; t < NB_; ++t) s += bf[r * NB_ + t] * bw[h * NB_ + t];
    tab[h * 4095 + d] = s;
}

// ---------------- NT GEMM: C[M][N] = alpha * A[M][K] @ B[N][K]^T ----------------
template <typename OutT>
__global__ __launch_bounds__(256) void gemm_nt(const f16* __restrict__ A,
                                               const f16* __restrict__ Bm,
                                               OutT* __restrict__ C,
                                               int M, int N, int K, float alpha) {
    __shared__ __align__(16) f16 As[128][32];
    __shared__ __align__(16) f16 Bs[128][32];
    const int tiles_n = N >> 7;
    int tm = blockIdx.x / tiles_n, tn = blockIdx.x % tiles_n;
    int m0 = tm << 7, n0 = tn << 7;
    int t = threadIdx.x;
    int w = t >> 6, l = t & 63;
    int wr = w >> 1, wc = w & 1;
    int fr = l & 15, fc = (l >> 4) << 3;
    f32x4 acc[4][4] = {};

    for (int k0 = 0; k0 < K; k0 += 32) {
#pragma unroll
        for (int uu = 0; uu < 2; ++uu) {
            int u = t + uu * 256;
            int row = u >> 2, c = (u & 3) << 3;
            *reinterpret_cast<f16x8*>(&As[row][c]) =
                *reinterpret_cast<const f16x8*>(&A[(size_t)(m0 + row) * K + k0 + c]);
            *reinterpret_cast<f16x8*>(&Bs[row][c]) =
                *reinterpret_cast<const f16x8*>(&Bm[(size_t)(n0 + row) * K + k0 + c]);
        }
        __syncthreads();
        f16x8 af[4], bfv[4];
#pragma unroll
        for (int m = 0; m < 4; ++m)
            af[m] = *reinterpret_cast<const f16x8*>(&As[wr * 64 + m * 16 + fr][fc]);
#pragma unroll
        for (int n = 0; n < 4; ++n)
            bfv[n] = *reinterpret_cast<const f16x8*>(&Bs[wc * 64 + n * 16 + fr][fc]);
#pragma unroll
        for (int m = 0; m < 4; ++m)
#pragma unroll
            for (int n = 0; n < 4; ++n)
                acc[m][n] = __builtin_amdgcn_mfma_f32_16x16x32_f16(af[m], bfv[n], acc[m][n], 0, 0, 0);
        __syncthreads();
    }
    int cc = l & 15, cr = (l >> 4) << 2;
#pragma unroll
    for (int m = 0; m < 4; ++m)
#pragma unroll
        for (int n = 0; n < 4; ++n)
#pragma unroll
            for (int j = 0; j < 4; ++j) {
                int rg = m0 + wr * 64 + m * 16 + cr + j;
                int cg = n0 + wc * 64 + n * 16 + cc;
                C[(size_t)rg * N + cg] = (OutT)(acc[m][n][j] * alpha);
            }
}

// ---------------- attention: two-pass exact softmax, small-LDS, high occupancy ----------------
// Block: 256 threads (4 waves), 16 q-rows. Wave w handles k-slice w*16 within 64-wide k-blocks.
// Pass 1: online (max, sum) per q-row in registers.  Pass 2: recompute scores (deterministic),
// write normalized attn straight to HBM, stage p in small LDS for PV A-fragments, accumulate PV.
__global__ __launch_bounds__(256, 4) void attn_kernel(const f16* __restrict__ qp,
                                                      const f16* __restrict__ kp,
                                                      const f16* __restrict__ vp,
                                                      const float* __restrict__ biasTab,
                                                      float* __restrict__ attn_out,
                                                      f16* __restrict__ ctx_out) {
    __shared__ __align__(16) f16 Ks[64][72];    // 9216 B
    __shared__ __align__(16) f16 VsT[64][72];   // 9216 B (transposed V tile)
    __shared__ __align__(16) f16 psh[16][80];   // 2560 B (p for PV A-fragments)
    __shared__ float red_m[16][4];
    __shared__ float red_l[16][4];
    __shared__ float m_s[16], linv_s[16];

    // XCD-chunked swizzle: 3072 = 8 * 384; blocks sharing (b,h) land on one XCD's L2
    int orig = blockIdx.x;
    int blk = (orig & 7) * 384 + (orig >> 3);
    int qt = blk & 127;
    int bh = blk >> 7;
    int h = bh % H_;
    int b = bh / H_;
    int q0 = qt << 4;

    int t = threadIdx.x;
    int w = t >> 6, l = t & 63;
    int fr = l & 15, fc = (l >> 4) << 3;
    int qrb = (l >> 4) << 2;

    const size_t rowbase = (size_t)b * S_ * QKV_LD + (size_t)h * HS;

    // Q fragments held in registers for the whole kernel (Wq pre-scaled by 1/8)
    f16x8 qf0, qf1;
    {
        const f16* qrow = qp + rowbase + (size_t)(q0 + fr) * QKV_LD;
        qf0 = *reinterpret_cast<const f16x8*>(qrow + fc);
        qf1 = *reinterpret_cast<const f16x8*>(qrow + 32 + fc);
    }

    const float* btab = biasTab + h * 4095 + 2047 - q0;

    // ---------------- pass 1: online (m, l) ----------------
    float m[4] = {-3.0e38f, -3.0e38f, -3.0e38f, -3.0e38f};
    float lsum[4] = {0.f, 0.f, 0.f, 0.f};

    for (int kb0 = 0; kb0 < S_; kb0 += 64) {
        {
            int row = t >> 3, c = (t & 7) << 3;
            *reinterpret_cast<f16x8*>(&Ks[row][c]) =
                *reinterpret_cast<const f16x8*>(kp + rowbase + (size_t)(kb0 + row) * QKV_LD + c);
            *reinterpret_cast<f16x8*>(&Ks[row + 32][c]) =
                *reinterpret_cast<const f16x8*>(kp + rowbase + (size_t)(kb0 + row + 32) * QKV_LD + c);
        }
        __syncthreads();
        f16x8 b0 = *reinterpret_cast<const f16x8*>(&Ks[w * 16 + fr][fc]);
        f16x8 b1 = *reinterpret_cast<const f16x8*>(&Ks[w * 16 + fr][32 + fc]);
        f32x4 s = {};
        s = __builtin_amdgcn_mfma_f32_16x16x32_f16(qf0, b0, s, 0, 0, 0);
        s = __builtin_amdgcn_mfma_f32_16x16x32_f16(qf1, b1, s, 0, 0, 0);
        int kk = kb0 + w * 16 + fr;
#pragma unroll
        for (int j = 0; j < 4; ++j) {
            float sv = s[j] + btab[kk - (qrb + j)];
            float d = sv - m[j];
            if (d > 0.f) {                       // new max (defer-style: 1 exp in common path)
                lsum[j] = lsum[j] * __expf(-d) + 1.f;
                m[j] = sv;
            } else {
                lsum[j] += __expf(d);
            }
        }
        __syncthreads();
    }

    // cross-lane merge over the 16 lanes sharing the same 4 q-rows
#pragma unroll
    for (int off = 1; off < 16; off <<= 1) {
#pragma unroll
        for (int j = 0; j < 4; ++j) {
            float mo = __shfl_xor(m[j], off);
            float lo = __shfl_xor(lsum[j], off);
            float mn = fmaxf(m[j], mo);
            lsum[j] = lsum[j] * __expf(m[j] - mn) + lo * __expf(mo - mn);
            m[j] = mn;
        }
    }
    if (fr == 0) {
#pragma unroll
        for (int j = 0; j < 4; ++j) { red_m[qrb + j][w] = m[j]; red_l[qrb + j][w] = lsum[j]; }
    }
    __syncthreads();
    if (t < 16) {
        float mf = red_m[t][0];
#pragma unroll
        for (int ww = 1; ww < 4; ++ww) mf = fmaxf(mf, red_m[t][ww]);
        float lf = 0.f;
#pragma unroll
        for (int ww = 0; ww < 4; ++ww) lf += red_l[t][ww] * __expf(red_m[t][ww] - mf);
        m_s[t] = mf;
        linv_s[t] = 1.0f / lf;
    }
    __syncthreads();
    float mrow[4], lirow[4];
#pragma unroll
    for (int j = 0; j < 4; ++j) { mrow[j] = m_s[qrb + j]; lirow[j] = linv_s[qrb + j]; }

    // ---------------- pass 2: recompute, normalize, write attn, PV ----------------
    f32x4 oacc = {};
    float* aout = attn_out + (((size_t)b * H_ + h) * S_ + q0) * S_;

    for (int kb0 = 0; kb0 < S_; kb0 += 64) {
        {
            int row = t >> 3, c = (t & 7) << 3;
            *reinterpret_cast<f16x8*>(&Ks[row][c]) =
                *reinterpret_cast<const f16x8*>(kp + rowbase + (size_t)(kb0 + row) * QKV_LD + c);
            *reinterpret_cast<f16x8*>(&Ks[row + 32][c]) =
                *reinterpret_cast<const f16x8*>(kp + rowbase + (size_t)(kb0 + row + 32) * QKV_LD + c);
            int cv = t >> 2, v0 = (t & 3) << 4;
            const f16* src = vp + rowbase + (size_t)(kb0 + cv) * QKV_LD + v0;
            __align__(16) f16 tmp[16];
            *reinterpret_cast<f16x8*>(tmp)     = *reinterpret_cast<const f16x8*>(src);
            *reinterpret_cast<f16x8*>(tmp + 8) = *reinterpret_cast<const f16x8*>(src + 8);
#pragma unroll
            for (int i2 = 0; i2 < 16; ++i2) VsT[v0 + i2][cv] = tmp[i2];
        }
        __syncthreads();
        f16x8 b0 = *reinterpret_cast<const f16x8*>(&Ks[w * 16 + fr][fc]);
        f16x8 b1 = *reinterpret_cast<const f16x8*>(&Ks[w * 16 + fr][32 + fc]);
        f32x4 s = {};
        s = __builtin_amdgcn_mfma_f32_16x16x32_f16(qf0, b0, s, 0, 0, 0);
        s = __builtin_amdgcn_mfma_f32_16x16x32_f16(qf1, b1, s, 0, 0, 0);
        int kk = kb0 + w * 16 + fr;
#pragma unroll
        for (int j = 0; j < 4; ++j) {
            float sv = s[j] + btab[kk - (qrb + j)];
            float p = __expf(sv - mrow[j]) * lirow[j];
            aout[(size_t)(qrb + j) * S_ + kk] = p;           // 16-lane 64B coalesced segments
            psh[qrb + j][(w << 4) + fr] = (f16)p;
        }
        __syncthreads();
        // PV: wave w owns v-slice [w*16, w*16+16)
        f16x8 pa0 = *reinterpret_cast<const f16x8*>(&psh[fr][fc]);
        f16x8 pa1 = *reinterpret_cast<const f16x8*>(&psh[fr][32 + fc]);
        f16x8 vf0 = *reinterpret_cast<const f16x8*>(&VsT[(w << 4) + fr][fc]);
        f16x8 vf1 = *reinterpret_cast<const f16x8*>(&VsT[(w << 4) + fr][32 + fc]);
        oacc = __builtin_amdgcn_mfma_f32_16x16x32_f16(pa0, vf0, oacc, 0, 0, 0);
        oacc = __builtin_amdgcn_mfma_f32_16x16x32_f16(pa1, vf1, oacc, 0, 0, 0);
        __syncthreads();
    }

    // ctx write: D col = l&15 -> v-local, row = qrb+j
    {
        f16* crow = ctx_out + ((size_t)b * S_ + q0) * DMODEL + h * HS + (w << 4) + fr;
#pragma unroll
        for (int j = 0; j < 4; ++j)
            crow[(size_t)(qrb + j) * DMODEL] = (f16)oacc[j];
    }
}

// ---------------- launch ----------------
extern "C" void kernel_launch(void* const* d_in, const int* in_sizes, int n_in,
                              void* d_out, int out_size, void* d_ws, size_t ws_size,
                              hipStream_t stream) {
    const float* x     = (const float*)d_in[0];
    const float* Wq    = (const float*)d_in[1];
    const float* Wk    = (const float*)d_in[2];
    const float* Wv    = (const float*)d_in[3];
    const float* Wo    = (const float*)d_in[4];
    const float* bw    = (const float*)d_in[5];
    const float* bfeat = (const float*)d_in[6];

    char* ws = (char*)d_ws;
    f16*   xb      = (f16*)(ws + 0);           // 4096x768      6,291,456 B
    f16*   qkv     = (f16*)(ws + 6291456);     // 4096x2304    18,874,368 B
    f16*   ctx     = (f16*)(ws + 25165824);    // 4096x768      6,291,456 B
    f16*   wqkv16  = (f16*)(ws + 31457280);    // 2304x768      3,538,944 B
    f16*   wo16    = (f16*)(ws + 34996224);    // 768x768       1,179,648 B
    float* biasTab = (float*)(ws + 36175872);  // 12x4095         196,560 B

    float* out0 = (float*)d_out;
    float* attn = out0 + (size_t)B_ * S_ * DMODEL;

    cast_f16_kernel<<<3072, 256, 0, stream>>>(x, xb, 786432, 1.0f);
    cast_f16_kernel<<<576, 256, 0, stream>>>(Wq, wqkv16 + 0,        147456, 0.125f);
    cast_f16_kernel<<<576, 256, 0, stream>>>(Wk, wqkv16 + 589824,   147456, 1.0f);
    cast_f16_kernel<<<576, 256, 0, stream>>>(Wv, wqkv16 + 1179648,  147456, 1.0f);
    cast_f16_kernel<<<576, 256, 0, stream>>>(Wo, wo16,              147456, 1.0f);
    bias_table_kernel<<<192, 256, 0, stream>>>(bw, bfeat, biasTab);

    gemm_nt<f16><<<32 * 18, 256, 0, stream>>>(xb, wqkv16, qkv, 4096, QKV_LD, 768, 1.0f);

    attn_kernel<<<B_ * H_ * (S_ / 16), 256, 0, stream>>>(
        qkv + 0, qkv + 768, qkv + 1536, biasTab, attn, ctx);

    gemm_nt<float><<<32 * 6, 256, 0, stream>>>(ctx, wo16, out0, 4096, DMODEL, 768, 1.0f);
}

// Round 3
// 211.088 us; speedup vs baseline: 3.8363x; 1.3660x over previous
//
#include <hip/hip_runtime.h>

typedef _Float16 f16;
typedef __attribute__((ext_vector_type(8))) _Float16 f16x8;
typedef __attribute__((ext_vector_type(4))) float f32x4;
typedef __attribute__((ext_vector_type(16))) float f32x16;

#define B_ 2
#define S_ 2048
#define DMODEL 768
#define H_ 12
#define HS 64
#define NB_ 16
#define QKV_LD 2304   // q,k,v concatenated columns

#define ZERO16 {0.f,0.f,0.f,0.f,0.f,0.f,0.f,0.f,0.f,0.f,0.f,0.f,0.f,0.f,0.f,0.f}

// ---------------- cast fp32 -> fp16 (optionally scaled) ----------------
__global__ __launch_bounds__(256) void cast_f16_kernel(const float* __restrict__ in,
                                                       f16* __restrict__ out,
                                                       int n4, float scale) {
    int i = blockIdx.x * 256 + threadIdx.x;
    if (i >= n4) return;
    float4 v = reinterpret_cast<const float4*>(in)[i];
    union { f16 h[4]; unsigned long long u; } o;
    o.h[0] = (f16)(v.x * scale);
    o.h[1] = (f16)(v.y * scale);
    o.h[2] = (f16)(v.z * scale);
    o.h[3] = (f16)(v.w * scale);
    reinterpret_cast<unsigned long long*>(out)[i] = o.u;
}

// ---------------- relative-position bias table (log2-domain): tab[h][d]*log2(e) ----------------
__global__ __launch_bounds__(256) void bias_table_kernel(const float* __restrict__ bw,
                                                         const float* __restrict__ bf,
                                                         float* __restrict__ tab) {
    int idx = blockIdx.x * 256 + threadIdx.x;
    if (idx >= H_ * 4095) return;
    int h = idx / 4095, d = idx % 4095;
    int rel = d - 2047;
    rel = min(1000, max(-1000, rel));
    int r = rel + 1000;
    float s = 0.f;
#pragma unroll
    for (int t = 0; t < NB_; ++t) s += bf[r * NB_ + t] * bw[h * NB_ + t];
    tab[h * 4095 + d] = s * 1.44269504088896f;   // log2(e)
}

// ---------------- NT GEMM: C[M][N] = alpha * A[M][K] @ B[N][K]^T ----------------
template <typename OutT>
__global__ __launch_bounds__(256) void gemm_nt(const f16* __restrict__ A,
                                               const f16* __restrict__ Bm,
                                               OutT* __restrict__ C,
                                               int M, int N, int K, float alpha) {
    __shared__ __align__(16) f16 As[128][32];
    __shared__ __align__(16) f16 Bs[128][32];
    const int tiles_n = N >> 7;
    int tm = blockIdx.x / tiles_n, tn = blockIdx.x % tiles_n;
    int m0 = tm << 7, n0 = tn << 7;
    int t = threadIdx.x;
    int w = t >> 6, l = t & 63;
    int wr = w >> 1, wc = w & 1;
    int fr = l & 15, fc = (l >> 4) << 3;
    f32x4 acc[4][4] = {};

    for (int k0 = 0; k0 < K; k0 += 32) {
#pragma unroll
        for (int uu = 0; uu < 2; ++uu) {
            int u = t + uu * 256;
            int row = u >> 2, c = (u & 3) << 3;
            *reinterpret_cast<f16x8*>(&As[row][c]) =
                *reinterpret_cast<const f16x8*>(&A[(size_t)(m0 + row) * K + k0 + c]);
            *reinterpret_cast<f16x8*>(&Bs[row][c]) =
                *reinterpret_cast<const f16x8*>(&Bm[(size_t)(n0 + row) * K + k0 + c]);
        }
        __syncthreads();
        f16x8 af[4], bfv[4];
#pragma unroll
        for (int m = 0; m < 4; ++m)
            af[m] = *reinterpret_cast<const f16x8*>(&As[wr * 64 + m * 16 + fr][fc]);
#pragma unroll
        for (int n = 0; n < 4; ++n)
            bfv[n] = *reinterpret_cast<const f16x8*>(&Bs[wc * 64 + n * 16 + fr][fc]);
#pragma unroll
        for (int m = 0; m < 4; ++m)
#pragma unroll
            for (int n = 0; n < 4; ++n)
                acc[m][n] = __builtin_amdgcn_mfma_f32_16x16x32_f16(af[m], bfv[n], acc[m][n], 0, 0, 0);
        __syncthreads();
    }
    int cc = l & 15, cr = (l >> 4) << 2;
#pragma unroll
    for (int m = 0; m < 4; ++m)
#pragma unroll
        for (int n = 0; n < 4; ++n)
#pragma unroll
            for (int j = 0; j < 4; ++j) {
                int rg = m0 + wr * 64 + m * 16 + cr + j;
                int cg = n0 + wc * 64 + n * 16 + cc;
                C[(size_t)rg * N + cg] = (OutT)(acc[m][n][j] * alpha);
            }
}

// ---------------- attention v3: 64q x 64k fat tiles, 32x32x16 MFMA, 2-pass exact ----------------
// Block: 256 threads = 4 waves in 2x2 (wq, wk) quadrant grid over a 64-row q-tile.
// Scores in log2 domain (Wq and bias pre-scaled by log2e) -> single v_exp_f32 per exp.
// Pass 1: online per-reg (m,l); shfl merge + LDS merge once. Pass 2: recompute, write
// normalized attn to HBM, p->LDS (f16) for PV A-fragments, accumulate O.
__global__ __launch_bounds__(256, 3) void attn_kernel(const f16* __restrict__ qp,
                                                      const f16* __restrict__ kp,
                                                      const f16* __restrict__ vp,
                                                      const float* __restrict__ biasTab,
                                                      float* __restrict__ attn_out,
                                                      f16* __restrict__ ctx_out) {
    __shared__ __align__(16) f16 Ks[64][72];     // 9216 B
    __shared__ __align__(16) f16 VsT[64][72];    // 9216 B (transposed V tile)
    __shared__ __align__(16) f16 psh[64][72];    // 9216 B (normalized p, f16)
    __shared__ float bias_l[2112];               // 8448 B (bias slice, log2 domain)
    __shared__ float red_m[64][2], red_l[64][2];
    __shared__ float m_s[64], li_s[64];

    // XCD-chunked swizzle: 768 = 8 * 96; same-(b,h) blocks share an XCD's L2
    int orig = blockIdx.x;
    int blk = (orig & 7) * 96 + (orig >> 3);
    int qt = blk & 31;
    int bh = blk >> 5;
    int h = bh % H_;
    int b = bh / H_;
    int q0 = qt << 6;

    int t = threadIdx.x;
    int w = t >> 6, l = t & 63;
    int wq = w >> 1, wk = w & 1;
    int col = l & 31;
    int hi = l >> 5;
    int hi4 = hi << 2, hi8 = hi << 3;

    const size_t rowbase = (size_t)b * S_ * QKV_LD + (size_t)h * HS;

    // Q fragments (A-operand), held whole kernel: row = q0+wq*32+col, k-chunk ci*16+hi8
    f16x8 qf[4];
    {
        const f16* qrow = qp + rowbase + (size_t)(q0 + wq * 32 + col) * QKV_LD + hi8;
#pragma unroll
        for (int ci = 0; ci < 4; ++ci) qf[ci] = *reinterpret_cast<const f16x8*>(qrow + ci * 16);
    }

    // stage bias slice: bias_l[i] = biasTab[h][i + 1984 - q0], i in [0,2112)
    {
        const float* bt = biasTab + h * 4095 + (1984 - q0);
        for (int i = t; i < 2112; i += 256) bias_l[i] = bt[i];
    }

    float mreg[16], lreg[16];
#pragma unroll
    for (int r = 0; r < 16; ++r) { mreg[r] = -3.0e38f; lreg[r] = 0.f; }

    // ---------------- pass 1: online (m,l) ----------------
    for (int kb0 = 0; kb0 < S_; kb0 += 64) {
        {
            int row = t >> 3, c = (t & 7) << 3;
            const f16* kb = kp + rowbase + (size_t)(kb0 + row) * QKV_LD + c;
            *reinterpret_cast<f16x8*>(&Ks[row][c]) = *reinterpret_cast<const f16x8*>(kb);
            *reinterpret_cast<f16x8*>(&Ks[row + 32][c]) =
                *reinterpret_cast<const f16x8*>(kb + (size_t)32 * QKV_LD);
        }
        __syncthreads();
        f32x16 s = ZERO16;
#pragma unroll
        for (int ci = 0; ci < 4; ++ci) {
            f16x8 kf = *reinterpret_cast<const f16x8*>(&Ks[wk * 32 + col][ci * 16 + hi8]);
            s = __builtin_amdgcn_mfma_f32_32x32x16_f16(qf[ci], kf, s, 0, 0, 0);
        }
        int kcol = kb0 + wk * 32 + col;
        const float* bl = bias_l + (kcol - (wq * 32 + hi4) + 63);
#pragma unroll
        for (int r = 0; r < 16; ++r) {
            const int cr = (r & 3) + 8 * (r >> 2);
            float sv = s[r] + bl[-cr];
            float d = sv - mreg[r];
            float e = __builtin_amdgcn_exp2f(-fabsf(d));
            bool up = d > 0.f;
            lreg[r] = up ? (lreg[r] * e + 1.f) : (lreg[r] + e);
            mreg[r] = up ? sv : mreg[r];
        }
        __syncthreads();
    }

    // merge across the 32 lanes (k-cols) of each half
#pragma unroll
    for (int off = 1; off < 32; off <<= 1) {
#pragma unroll
        for (int r = 0; r < 16; ++r) {
            float mo = __shfl_xor(mreg[r], off);
            float lo = __shfl_xor(lreg[r], off);
            float mn = fmaxf(mreg[r], mo);
            lreg[r] = lreg[r] * __builtin_amdgcn_exp2f(mreg[r] - mn)
                    + lo * __builtin_amdgcn_exp2f(mo - mn);
            mreg[r] = mn;
        }
    }
    if (col == 0) {
#pragma unroll
        for (int r = 0; r < 16; ++r) {
            int row = wq * 32 + (r & 3) + 8 * (r >> 2) + hi4;
            red_m[row][wk] = mreg[r];
            red_l[row][wk] = lreg[r];
        }
    }
    __syncthreads();
    if (t < 64) {
        float m0 = red_m[t][0], m1 = red_m[t][1];
        float mf = fmaxf(m0, m1);
        float lf = red_l[t][0] * __builtin_amdgcn_exp2f(m0 - mf)
                 + red_l[t][1] * __builtin_amdgcn_exp2f(m1 - mf);
        m_s[t] = mf;
        li_s[t] = 1.0f / lf;
    }
    __syncthreads();
#pragma unroll
    for (int r = 0; r < 16; ++r) {
        int row = wq * 32 + (r & 3) + 8 * (r >> 2) + hi4;
        mreg[r] = m_s[row];      // final row max (log2 domain)
        lreg[r] = li_s[row];     // 1 / denom
    }

    // ---------------- pass 2: recompute, write attn, PV ----------------
    f32x16 oacc = ZERO16;
    float* aout = attn_out + (((size_t)b * H_ + h) * S_ + q0) * S_;

    for (int kb0 = 0; kb0 < S_; kb0 += 64) {
        {
            int row = t >> 3, c = (t & 7) << 3;
            const f16* kb = kp + rowbase + (size_t)(kb0 + row) * QKV_LD + c;
            *reinterpret_cast<f16x8*>(&Ks[row][c]) = *reinterpret_cast<const f16x8*>(kb);
            *reinterpret_cast<f16x8*>(&Ks[row + 32][c]) =
                *reinterpret_cast<const f16x8*>(kb + (size_t)32 * QKV_LD);
            int cv = t >> 2, v0 = (t & 3) << 4;
            const f16* src = vp + rowbase + (size_t)(kb0 + cv) * QKV_LD + v0;
            __align__(16) f16 tmp[16];
            *reinterpret_cast<f16x8*>(tmp)     = *reinterpret_cast<const f16x8*>(src);
            *reinterpret_cast<f16x8*>(tmp + 8) = *reinterpret_cast<const f16x8*>(src + 8);
#pragma unroll
            for (int i2 = 0; i2 < 16; ++i2) VsT[v0 + i2][cv] = tmp[i2];
        }
        __syncthreads();
        f32x16 s = ZERO16;
#pragma unroll
        for (int ci = 0; ci < 4; ++ci) {
            f16x8 kf = *reinterpret_cast<const f16x8*>(&Ks[wk * 32 + col][ci * 16 + hi8]);
            s = __builtin_amdgcn_mfma_f32_32x32x16_f16(qf[ci], kf, s, 0, 0, 0);
        }
        int kcol = kb0 + wk * 32 + col;
        const float* bl = bias_l + (kcol - (wq * 32 + hi4) + 63);
#pragma unroll
        for (int r = 0; r < 16; ++r) {
            const int cr = (r & 3) + 8 * (r >> 2);
            int row = wq * 32 + cr + hi4;
            float sv = s[r] + bl[-cr];
            float p = __builtin_amdgcn_exp2f(sv - mreg[r]) * lreg[r];
            aout[(size_t)row * S_ + kcol] = p;          // 128B segments per reg-store
            psh[row][wk * 32 + col] = (f16)p;
        }
        __syncthreads();
#pragma unroll
        for (int ci = 0; ci < 4; ++ci) {
            f16x8 pa = *reinterpret_cast<const f16x8*>(&psh[wq * 32 + col][ci * 16 + hi8]);
            f16x8 vf = *reinterpret_cast<const f16x8*>(&VsT[wk * 32 + col][ci * 16 + hi8]);
            oacc = __builtin_amdgcn_mfma_f32_32x32x16_f16(pa, vf, oacc, 0, 0, 0);
        }
        __syncthreads();
    }

    // ctx write: O quadrant rows = q, cols = v (lane=col)
    {
        f16* cbase = ctx_out + ((size_t)b * S_ + q0) * DMODEL + h * HS + wk * 32 + col;
#pragma unroll
        for (int r = 0; r < 16; ++r) {
            int row = wq * 32 + (r & 3) + 8 * (r >> 2) + hi4;
            cbase[(size_t)row * DMODEL] = (f16)oacc[r];
        }
    }
}

// ---------------- launch ----------------
extern "C" void kernel_launch(void* const* d_in, const int* in_sizes, int n_in,
                              void* d_out, int out_size, void* d_ws, size_t ws_size,
                              hipStream_t stream) {
    const float* x     = (const float*)d_in[0];
    const float* Wq    = (const float*)d_in[1];
    const float* Wk    = (const float*)d_in[2];
    const float* Wv    = (const float*)d_in[3];
    const float* Wo    = (const float*)d_in[4];
    const float* bw    = (const float*)d_in[5];
    const float* bfeat = (const float*)d_in[6];

    char* ws = (char*)d_ws;
    f16*   xb      = (f16*)(ws + 0);           // 4096x768      6,291,456 B
    f16*   qkv     = (f16*)(ws + 6291456);     // 4096x2304    18,874,368 B
    f16*   ctx     = (f16*)(ws + 25165824);    // 4096x768      6,291,456 B
    f16*   wqkv16  = (f16*)(ws + 31457280);    // 2304x768      3,538,944 B
    f16*   wo16    = (f16*)(ws + 34996224);    // 768x768       1,179,648 B
    float* biasTab = (float*)(ws + 36175872);  // 12x4095         196,560 B

    float* out0 = (float*)d_out;
    float* attn = out0 + (size_t)B_ * S_ * DMODEL;

    // casts; Wq folded scale = (1/sqrt(64)) * log2(e)  -> QK^T directly in log2 domain
    cast_f16_kernel<<<3072, 256, 0, stream>>>(x, xb, 786432, 1.0f);
    cast_f16_kernel<<<576, 256, 0, stream>>>(Wq, wqkv16 + 0,        147456, 0.18033688011112f);
    cast_f16_kernel<<<576, 256, 0, stream>>>(Wk, wqkv16 + 589824,   147456, 1.0f);
    cast_f16_kernel<<<576, 256, 0, stream>>>(Wv, wqkv16 + 1179648,  147456, 1.0f);
    cast_f16_kernel<<<576, 256, 0, stream>>>(Wo, wo16,              147456, 1.0f);
    bias_table_kernel<<<192, 256, 0, stream>>>(bw, bfeat, biasTab);

    gemm_nt<f16><<<32 * 18, 256, 0, stream>>>(xb, wqkv16, qkv, 4096, QKV_LD, 768, 1.0f);

    attn_kernel<<<B_ * H_ * (S_ / 64), 256, 0, stream>>>(
        qkv + 0, qkv + 768, qkv + 1536, biasTab, attn, ctx);

    gemm_nt<float><<<32 * 6, 256, 0, stream>>>(ctx, wo16, out0, 4096, DMODEL, 768, 1.0f);
}

// Round 4
// 197.992 us; speedup vs baseline: 4.0900x; 1.0661x over previous
//
#include <hip/hip_runtime.h>

typedef _Float16 f16;
typedef __attribute__((ext_vector_type(8))) _Float16 f16x8;
typedef __attribute__((ext_vector_type(4))) float f32x4;
typedef __attribute__((ext_vector_type(16))) float f32x16;

#define B_ 2
#define S_ 2048
#define DMODEL 768
#define H_ 12
#define HS 64
#define NB_ 16
#define QKV_LD 2304   // q,k,v concatenated columns

#define ZERO16 {0.f,0.f,0.f,0.f,0.f,0.f,0.f,0.f,0.f,0.f,0.f,0.f,0.f,0.f,0.f,0.f}

// ---------------- cast fp32 -> fp16 (optionally scaled) ----------------
__global__ __launch_bounds__(256) void cast_f16_kernel(const float* __restrict__ in,
                                                       f16* __restrict__ out,
                                                       int n4, float scale) {
    int i = blockIdx.x * 256 + threadIdx.x;
    if (i >= n4) return;
    float4 v = reinterpret_cast<const float4*>(in)[i];
    union { f16 h[4]; unsigned long long u; } o;
    o.h[0] = (f16)(v.x * scale);
    o.h[1] = (f16)(v.y * scale);
    o.h[2] = (f16)(v.z * scale);
    o.h[3] = (f16)(v.w * scale);
    reinterpret_cast<unsigned long long*>(out)[i] = o.u;
}

// fused cast of Wq (scaled), Wk, Wv into contiguous wqkv16
__global__ __launch_bounds__(256) void wcast_kernel(const float* __restrict__ Wq,
                                                    const float* __restrict__ Wk,
                                                    const float* __restrict__ Wv,
                                                    f16* __restrict__ dst) {
    int i = blockIdx.x * 256 + threadIdx.x;   // [0, 3*147456)
    const float* src;
    float scale = 1.0f;
    int j = i;
    if (i < 147456)      { src = Wq; scale = 0.18033688011112f; }  // (1/8)*log2(e)
    else if (i < 294912) { src = Wk; j = i - 147456; }
    else                 { src = Wv; j = i - 294912; }
    float4 v = reinterpret_cast<const float4*>(src)[j];
    union { f16 h[4]; unsigned long long u; } o;
    o.h[0] = (f16)(v.x * scale);
    o.h[1] = (f16)(v.y * scale);
    o.h[2] = (f16)(v.z * scale);
    o.h[3] = (f16)(v.w * scale);
    reinterpret_cast<unsigned long long*>(dst)[i] = o.u;
}

// ---------------- relative-position bias table (log2-domain): tab[h][d]*log2(e) ----------------
__global__ __launch_bounds__(256) void bias_table_kernel(const float* __restrict__ bw,
                                                         const float* __restrict__ bf,
                                                         float* __restrict__ tab) {
    int idx = blockIdx.x * 256 + threadIdx.x;
    if (idx >= H_ * 4095) return;
    int h = idx / 4095, d = idx % 4095;
    int rel = d - 2047;
    rel = min(1000, max(-1000, rel));
    int r = rel + 1000;
    float s = 0.f;
#pragma unroll
    for (int t = 0; t < NB_; ++t) s += bf[r * NB_ + t] * bw[h * NB_ + t];
    tab[h * 4095 + d] = s * 1.44269504088896f;   // log2(e)
}

// ---------------- NT GEMM: C[M][N] = alpha * A[M][K] @ B[N][K]^T ----------------
// LDS padded [128][40] (80 B rows, 16B-aligned): 2-way bank aliasing only.
template <typename OutT>
__global__ __launch_bounds__(256) void gemm_nt(const f16* __restrict__ A,
                                               const f16* __restrict__ Bm,
                                               OutT* __restrict__ C,
                                               int M, int N, int K, float alpha) {
    __shared__ __align__(16) f16 As[128][40];
    __shared__ __align__(16) f16 Bs[128][40];
    const int tiles_n = N >> 7;
    int tm = blockIdx.x / tiles_n, tn = blockIdx.x % tiles_n;
    int m0 = tm << 7, n0 = tn << 7;
    int t = threadIdx.x;
    int w = t >> 6, l = t & 63;
    int wr = w >> 1, wc = w & 1;
    int fr = l & 15, fc = (l >> 4) << 3;
    f32x4 acc[4][4] = {};

    for (int k0 = 0; k0 < K; k0 += 32) {
#pragma unroll
        for (int uu = 0; uu < 2; ++uu) {
            int u = t + uu * 256;
            int row = u >> 2, c = (u & 3) << 3;
            *reinterpret_cast<f16x8*>(&As[row][c]) =
                *reinterpret_cast<const f16x8*>(&A[(size_t)(m0 + row) * K + k0 + c]);
            *reinterpret_cast<f16x8*>(&Bs[row][c]) =
                *reinterpret_cast<const f16x8*>(&Bm[(size_t)(n0 + row) * K + k0 + c]);
        }
        __syncthreads();
        f16x8 af[4], bfv[4];
#pragma unroll
        for (int m = 0; m < 4; ++m)
            af[m] = *reinterpret_cast<const f16x8*>(&As[wr * 64 + m * 16 + fr][fc]);
#pragma unroll
        for (int n = 0; n < 4; ++n)
            bfv[n] = *reinterpret_cast<const f16x8*>(&Bs[wc * 64 + n * 16 + fr][fc]);
#pragma unroll
        for (int m = 0; m < 4; ++m)
#pragma unroll
            for (int n = 0; n < 4; ++n)
                acc[m][n] = __builtin_amdgcn_mfma_f32_16x16x32_f16(af[m], bfv[n], acc[m][n], 0, 0, 0);
        __syncthreads();
    }
    int cc = l & 15, cr = (l >> 4) << 2;
#pragma unroll
    for (int m = 0; m < 4; ++m)
#pragma unroll
        for (int n = 0; n < 4; ++n)
#pragma unroll
            for (int j = 0; j < 4; ++j) {
                int rg = m0 + wr * 64 + m * 16 + cr + j;
                int cg = n0 + wc * 64 + n * 16 + cc;
                C[(size_t)rg * N + cg] = (OutT)(acc[m][n][j] * alpha);
            }
}

// ---------------- attention v4: no-max exact softmax (log2 domain), 2-pass ----------------
// Block: 256 threads = 4 waves, 2x2 (wq,wk) quadrants over a 64-row q-tile; 32x32x16 MFMA.
// Softmax shift-invariance: scores bounded (|s|<~30 in log2 domain) -> skip max entirely.
// Pass 1: row sums only (KVBLK=128, K-only staging). Pass 2: recompute, p = exp2(s)/sum,
// non-temporal store to attn, p->LDS f16 for PV.
__global__ __launch_bounds__(256, 4) void attn_kernel(const f16* __restrict__ qp,
                                                      const f16* __restrict__ kp,
                                                      const f16* __restrict__ vp,
                                                      const float* __restrict__ biasTab,
                                                      float* __restrict__ attn_out,
                                                      f16* __restrict__ ctx_out) {
    __shared__ union {
        f16 ks1[128][72];                        // pass 1: 128 k-rows      (18432 B)
        struct { f16 ks[64][72]; f16 vst[64][72]; } p2;  // pass 2          (18432 B)
    } ar;
    __shared__ __align__(16) f16 psh[64][72];    // 9216 B normalized p (f16)
    __shared__ float bias_l[2112];               // 8448 B bias slice (log2 domain)
    __shared__ float red_l[64][2];
    __shared__ float li_s[64];

    // XCD-chunked swizzle: 768 = 8 * 96
    int orig = blockIdx.x;
    int blk = (orig & 7) * 96 + (orig >> 3);
    int qt = blk & 31;
    int bh = blk >> 5;
    int h = bh % H_;
    int b = bh / H_;
    int q0 = qt << 6;

    int t = threadIdx.x;
    int w = t >> 6, l = t & 63;
    int wq = w >> 1, wk = w & 1;
    int col = l & 31;
    int hi = l >> 5;
    int hi4 = hi << 2, hi8 = hi << 3;

    const size_t rowbase = (size_t)b * S_ * QKV_LD + (size_t)h * HS;

    // Q fragments (A-operand), held whole kernel
    f16x8 qf[4];
    {
        const f16* qrow = qp + rowbase + (size_t)(q0 + wq * 32 + col) * QKV_LD + hi8;
#pragma unroll
        for (int ci = 0; ci < 4; ++ci) qf[ci] = *reinterpret_cast<const f16x8*>(qrow + ci * 16);
    }

    // stage bias slice: bias_l[i] = biasTab[h][i + 1984 - q0], used range [0, 2110]
    {
        const float* bt = biasTab + h * 4095 + (1984 - q0);
        for (int i = t; i < 2111; i += 256) bias_l[i] = bt[i];
    }

    float lsum[16];
#pragma unroll
    for (int r = 0; r < 16; ++r) lsum[r] = 0.f;

    // ---------------- pass 1: row sums ----------------
    for (int kb0 = 0; kb0 < S_; kb0 += 128) {
#pragma unroll
        for (int uu = 0; uu < 4; ++uu) {
            int u = (uu << 8) + t;
            int row = u >> 3, c = (u & 7) << 3;
            *reinterpret_cast<f16x8*>(&ar.ks1[row][c]) =
                *reinterpret_cast<const f16x8*>(kp + rowbase + (size_t)(kb0 + row) * QKV_LD + c);
        }
        __syncthreads();
#pragma unroll
        for (int half = 0; half < 2; ++half) {
            f32x16 s = ZERO16;
#pragma unroll
            for (int ci = 0; ci < 4; ++ci) {
                f16x8 kf = *reinterpret_cast<const f16x8*>(
                    &ar.ks1[half * 64 + wk * 32 + col][ci * 16 + hi8]);
                s = __builtin_amdgcn_mfma_f32_32x32x16_f16(qf[ci], kf, s, 0, 0, 0);
            }
            int kcol = kb0 + half * 64 + wk * 32 + col;
            const float* bl = bias_l + (kcol + 63 - (wq * 32 + hi4));
#pragma unroll
            for (int r = 0; r < 16; ++r) {
                const int cr = (r & 3) + 8 * (r >> 2);
                lsum[r] += __builtin_amdgcn_exp2f(s[r] + bl[-cr]);
            }
        }
        __syncthreads();
    }

    // reduce sums: 32 lanes (cols) -> LDS merge across wk halves
#pragma unroll
    for (int off = 1; off < 32; off <<= 1) {
#pragma unroll
        for (int r = 0; r < 16; ++r) lsum[r] += __shfl_xor(lsum[r], off);
    }
    if (col == 0) {
#pragma unroll
        for (int r = 0; r < 16; ++r)
            red_l[wq * 32 + (r & 3) + 8 * (r >> 2) + hi4][wk] = lsum[r];
    }
    __syncthreads();
    if (t < 64) li_s[t] = 1.0f / (red_l[t][0] + red_l[t][1]);
    __syncthreads();
    float lreg[16];
#pragma unroll
    for (int r = 0; r < 16; ++r) lreg[r] = li_s[wq * 32 + (r & 3) + 8 * (r >> 2) + hi4];

    // ---------------- pass 2: recompute, write attn, PV ----------------
    f32x16 oacc = ZERO16;
    float* aout = attn_out + (((size_t)b * H_ + h) * S_ + q0) * S_;

    for (int kb0 = 0; kb0 < S_; kb0 += 64) {
        {
            int row = t >> 3, c = (t & 7) << 3;
            const f16* kb = kp + rowbase + (size_t)(kb0 + row) * QKV_LD + c;
            *reinterpret_cast<f16x8*>(&ar.p2.ks[row][c]) = *reinterpret_cast<const f16x8*>(kb);
            *reinterpret_cast<f16x8*>(&ar.p2.ks[row + 32][c]) =
                *reinterpret_cast<const f16x8*>(kb + (size_t)32 * QKV_LD);
            int cv = t >> 2, v0 = (t & 3) << 4;
            const f16* src = vp + rowbase + (size_t)(kb0 + cv) * QKV_LD + v0;
            __align__(16) f16 tmp[16];
            *reinterpret_cast<f16x8*>(tmp)     = *reinterpret_cast<const f16x8*>(src);
            *reinterpret_cast<f16x8*>(tmp + 8) = *reinterpret_cast<const f16x8*>(src + 8);
#pragma unroll
            for (int i2 = 0; i2 < 16; ++i2) ar.p2.vst[v0 + i2][cv] = tmp[i2];
        }
        __syncthreads();
        f32x16 s = ZERO16;
#pragma unroll
        for (int ci = 0; ci < 4; ++ci) {
            f16x8 kf = *reinterpret_cast<const f16x8*>(&ar.p2.ks[wk * 32 + col][ci * 16 + hi8]);
            s = __builtin_amdgcn_mfma_f32_32x32x16_f16(qf[ci], kf, s, 0, 0, 0);
        }
        int kcol = kb0 + wk * 32 + col;
        const float* bl = bias_l + (kcol + 63 - (wq * 32 + hi4));
#pragma unroll
        for (int r = 0; r < 16; ++r) {
            const int cr = (r & 3) + 8 * (r >> 2);
            int row = wq * 32 + cr + hi4;
            float p = __builtin_amdgcn_exp2f(s[r] + bl[-cr]) * lreg[r];
            __builtin_nontemporal_store(p, &aout[(size_t)row * S_ + kcol]);
            psh[row][wk * 32 + col] = (f16)p;
        }
        __syncthreads();
#pragma unroll
        for (int ci = 0; ci < 4; ++ci) {
            f16x8 pa = *reinterpret_cast<const f16x8*>(&psh[wq * 32 + col][ci * 16 + hi8]);
            f16x8 vf = *reinterpret_cast<const f16x8*>(&ar.p2.vst[wk * 32 + col][ci * 16 + hi8]);
            oacc = __builtin_amdgcn_mfma_f32_32x32x16_f16(pa, vf, oacc, 0, 0, 0);
        }
        __syncthreads();
    }

    // ctx write
    {
        f16* cbase = ctx_out + ((size_t)b * S_ + q0) * DMODEL + h * HS + wk * 32 + col;
#pragma unroll
        for (int r = 0; r < 16; ++r) {
            int row = wq * 32 + (r & 3) + 8 * (r >> 2) + hi4;
            cbase[(size_t)row * DMODEL] = (f16)oacc[r];
        }
    }
}

// ---------------- launch ----------------
extern "C" void kernel_launch(void* const* d_in, const int* in_sizes, int n_in,
                              void* d_out, int out_size, void* d_ws, size_t ws_size,
                              hipStream_t stream) {
    const float* x     = (const float*)d_in[0];
    const float* Wq    = (const float*)d_in[1];
    const float* Wk    = (const float*)d_in[2];
    const float* Wv    = (const float*)d_in[3];
    const float* Wo    = (const float*)d_in[4];
    const float* bw    = (const float*)d_in[5];
    const float* bfeat = (const float*)d_in[6];

    char* ws = (char*)d_ws;
    f16*   xb      = (f16*)(ws + 0);           // 4096x768      6,291,456 B
    f16*   qkv     = (f16*)(ws + 6291456);     // 4096x2304    18,874,368 B
    f16*   ctx     = (f16*)(ws + 25165824);    // 4096x768      6,291,456 B
    f16*   wqkv16  = (f16*)(ws + 31457280);    // 2304x768      3,538,944 B
    f16*   wo16    = (f16*)(ws + 34996224);    // 768x768       1,179,648 B
    float* biasTab = (float*)(ws + 36175872);  // 12x4095         196,560 B

    float* out0 = (float*)d_out;
    float* attn = out0 + (size_t)B_ * S_ * DMODEL;

    cast_f16_kernel<<<3072, 256, 0, stream>>>(x, xb, 786432, 1.0f);
    wcast_kernel<<<1728, 256, 0, stream>>>(Wq, Wk, Wv, wqkv16);
    cast_f16_kernel<<<576, 256, 0, stream>>>(Wo, wo16, 147456, 1.0f);
    bias_table_kernel<<<192, 256, 0, stream>>>(bw, bfeat, biasTab);

    gemm_nt<f16><<<32 * 18, 256, 0, stream>>>(xb, wqkv16, qkv, 4096, QKV_LD, 768, 1.0f);

    attn_kernel<<<B_ * H_ * (S_ / 64), 256, 0, stream>>>(
        qkv + 0, qkv + 768, qkv + 1536, biasTab, attn, ctx);

    gemm_nt<float><<<32 * 6, 256, 0, stream>>>(ctx, wo16, out0, 4096, DMODEL, 768, 1.0f);
}

// Round 6
// 177.728 us; speedup vs baseline: 4.5564x; 1.1140x over previous
//
#include <hip/hip_runtime.h>

typedef _Float16 f16;
typedef __attribute__((ext_vector_type(8))) _Float16 f16x8;
typedef __attribute__((ext_vector_type(4))) float f32x4;
typedef __attribute__((ext_vector_type(16))) float f32x16;

#define B_ 2
#define S_ 2048
#define DMODEL 768
#define H_ 12
#define HS 64
#define NB_ 16
#define QKV_LD 2304   // q,k,v concatenated columns

#define ZERO16 {0.f,0.f,0.f,0.f,0.f,0.f,0.f,0.f,0.f,0.f,0.f,0.f,0.f,0.f,0.f,0.f}

// async global->LDS 16B: LDS dest = wave-uniform base + lane*16
__device__ __forceinline__ void gload16(const f16* g, f16* lds) {
    __builtin_amdgcn_global_load_lds((const __attribute__((address_space(1))) void*)g,
                                     (__attribute__((address_space(3))) void*)lds, 16, 0, 0);
}

// ---------------- fused prep: casts + bias table ----------------
// grid 5568: [0,3072) x | [3072,4800) Wq|Wk|Wv | [4800,5376) Wo | [5376,5568) bias
__global__ __launch_bounds__(256) void prep_kernel(const float* __restrict__ x,
                                                   const float* __restrict__ Wq,
                                                   const float* __restrict__ Wk,
                                                   const float* __restrict__ Wv,
                                                   const float* __restrict__ Wo,
                                                   const float* __restrict__ bw,
                                                   const float* __restrict__ bf,
                                                   f16* __restrict__ xb,
                                                   f16* __restrict__ wqkv16,
                                                   f16* __restrict__ wo16,
                                                   float* __restrict__ biasTab) {
    int bid = blockIdx.x;
    int t = threadIdx.x;
    if (bid < 5376) {
        const float* src;
        f16* dst;
        float scale = 1.0f;
        int i;
        if (bid < 3072) {            // x: 786432 float4
            i = bid * 256 + t; src = x; dst = xb;
        } else if (bid < 4800) {     // Wq|Wk|Wv: 3 x 147456 float4 -> contiguous wqkv16
            i = (bid - 3072) * 256 + t;
            dst = wqkv16;
            if (i < 147456)      { src = Wq; scale = 0.18033688011112f; }   // (1/8)*log2e
            else if (i < 294912) { src = Wk - 147456 * 4; }
            else                 { src = Wv - 294912 * 4; }
        } else {                     // Wo: 147456 float4
            i = (bid - 4800) * 256 + t; src = Wo; dst = wo16;
        }
        float4 v = reinterpret_cast<const float4*>(src)[i];
        union { f16 h[4]; unsigned long long u; } o;
        o.h[0] = (f16)(v.x * scale);
        o.h[1] = (f16)(v.y * scale);
        o.h[2] = (f16)(v.z * scale);
        o.h[3] = (f16)(v.w * scale);
        reinterpret_cast<unsigned long long*>(dst)[i] = o.u;
    } else {                         // bias table, log2 domain
        int idx = (bid - 5376) * 256 + t;
        if (idx >= H_ * 4095) return;
        int h = idx / 4095, d = idx % 4095;
        int rel = min(1000, max(-1000, d - 2047));
        int r = rel + 1000;
        float s = 0.f;
#pragma unroll
        for (int tt = 0; tt < NB_; ++tt) s += bf[r * NB_ + tt] * bw[h * NB_ + tt];
        biasTab[h * 4095 + d] = s * 1.44269504088896f;
    }
}

// ---------------- V transpose: vt[(b*H+h)*64 + v][token] = V[b][token][h*64+v] ----------------
__global__ __launch_bounds__(256) void vtrans_kernel(const f16* __restrict__ qkv,
                                                     f16* __restrict__ vt) {
    __shared__ f16 tile[64][72];
    int blk = blockIdx.x;            // (b*H+h)*32 + tb
    int tb = blk & 31;
    int bh = blk >> 5;
    int b = bh / H_;
    int tok0 = tb << 6;
    int t = threadIdx.x;
    const f16* src = qkv + (size_t)b * S_ * QKV_LD + 1536 + (bh - b * H_) * 64;
#pragma unroll
    for (int j = 0; j < 2; ++j) {
        int u = t + (j << 8);
        int r = u >> 3, c = (u & 7) << 3;
        *reinterpret_cast<f16x8*>(&tile[r][c]) =
            *reinterpret_cast<const f16x8*>(src + (size_t)(tok0 + r) * QKV_LD + c);
    }
    __syncthreads();
    f16* dst = vt + (size_t)bh * 64 * S_ + tok0;
#pragma unroll
    for (int j = 0; j < 2; ++j) {
        int u = t + (j << 8);
        int v = u >> 3, tc = (u & 7) << 3;
        union { f16 h8[8]; f16x8 v8; } o;
#pragma unroll
        for (int i = 0; i < 8; ++i) o.h8[i] = tile[tc + i][v];
        *reinterpret_cast<f16x8*>(&dst[(size_t)v * S_ + tc]) = o.v8;
    }
}

// ---------------- NT GEMM via global_load_lds, source-pre-swizzled chunks ----------------
template <typename OutT>
__global__ __launch_bounds__(256) void gemm_nt(const f16* __restrict__ A,
                                               const f16* __restrict__ Bm,
                                               OutT* __restrict__ C,
                                               int M, int N, int K, float alpha) {
    __shared__ __align__(16) f16 As[128 * 32];
    __shared__ __align__(16) f16 Bs[128 * 32];
    const int tiles_n = N >> 7;
    int tm = blockIdx.x / tiles_n, tn = blockIdx.x % tiles_n;
    int m0 = tm << 7, n0 = tn << 7;
    int t = threadIdx.x;
    int w = t >> 6, l = t & 63;
    int wr = w >> 1, wc = w & 1;
    int fr = l & 15, hi = l >> 4;
    f32x4 acc[4][4] = {};

    for (int k0 = 0; k0 < K; k0 += 32) {
#pragma unroll
        for (int j = 0; j < 2; ++j) {
            int u = t + (j << 8);
            int row = u >> 2, ch = u & 3;
            int gcol = k0 + ((ch ^ (row & 3)) << 3);
            gload16(&A[(size_t)(m0 + row) * K + gcol], As + (w << 9) + (j << 11));
            gload16(&Bm[(size_t)(n0 + row) * K + gcol], Bs + (w << 9) + (j << 11));
        }
        __syncthreads();
        f16x8 af[4], bfv[4];
#pragma unroll
        for (int m = 0; m < 4; ++m) {
            int row = wr * 64 + m * 16 + fr;
            af[m] = *reinterpret_cast<const f16x8*>(&As[row * 32 + ((hi ^ (fr & 3)) << 3)]);
        }
#pragma unroll
        for (int n = 0; n < 4; ++n) {
            int row = wc * 64 + n * 16 + fr;
            bfv[n] = *reinterpret_cast<const f16x8*>(&Bs[row * 32 + ((hi ^ (fr & 3)) << 3)]);
        }
#pragma unroll
        for (int m = 0; m < 4; ++m)
#pragma unroll
            for (int n = 0; n < 4; ++n)
                acc[m][n] = __builtin_amdgcn_mfma_f32_16x16x32_f16(af[m], bfv[n], acc[m][n], 0, 0, 0);
        __syncthreads();
    }
    int cc = l & 15, cr = (l >> 4) << 2;
#pragma unroll
    for (int m = 0; m < 4; ++m)
#pragma unroll
        for (int n = 0; n < 4; ++n)
#pragma unroll
            for (int j = 0; j < 4; ++j) {
                int rg = m0 + wr * 64 + m * 16 + cr + j;
                int cg = n0 + wc * 64 + n * 16 + cc;
                C[(size_t)rg * N + cg] = (OutT)(acc[m][n][j] * alpha);
            }
}

// ---------------- attention v5: no-max 2-pass, gload_lds staging, pre-transposed V ----------------
__global__ __launch_bounds__(256, 4) void attn_kernel(const f16* __restrict__ qp,
                                                      const f16* __restrict__ kp,
                                                      const f16* __restrict__ vt,
                                                      const float* __restrict__ biasTab,
                                                      float* __restrict__ attn_out,
                                                      f16* __restrict__ ctx_out) {
    __shared__ __align__(16) union {
        f16 ks1[128 * 64];                           // pass 1: 16384 B
        struct { f16 ks[64 * 64]; f16 vs[64 * 64]; } p2;
    } ar;
    __shared__ __align__(16) f16 psh[64][72];        // 9216 B
    __shared__ float bias_l[2112];                   // 8448 B
    __shared__ float red_l[64][2];
    __shared__ float li_s[64];

    // XCD-chunked swizzle: 768 = 8 * 96
    int orig = blockIdx.x;
    int blk = (orig & 7) * 96 + (orig >> 3);
    int qt = blk & 31;
    int bh = blk >> 5;
    int h = bh % H_;
    int b = bh / H_;
    int q0 = qt << 6;

    int t = threadIdx.x;
    int w = t >> 6, l = t & 63;
    int wq = w >> 1, wk = w & 1;
    int col = l & 31;
    int hi = l >> 5;
    int hi4 = hi << 2, hi8 = hi << 3;

    const size_t rowbase = (size_t)b * S_ * QKV_LD + (size_t)h * HS;
    const f16* vbase = vt + (size_t)bh * HS * S_;

    // Q fragments (A-operand), held whole kernel
    f16x8 qf[4];
    {
        const f16* qrow = qp + rowbase + (size_t)(q0 + wq * 32 + col) * QKV_LD + hi8;
#pragma unroll
        for (int ci = 0; ci < 4; ++ci) qf[ci] = *reinterpret_cast<const f16x8*>(qrow + ci * 16);
    }

    // stage bias slice: bias_l[i] = biasTab[h][i + 1984 - q0]
    {
        const float* bt = biasTab + h * 4095 + (1984 - q0);
        for (int i = t; i < 2111; i += 256) bias_l[i] = bt[i];
    }

    float lsum[16];
#pragma unroll
    for (int r = 0; r < 16; ++r) lsum[r] = 0.f;

    // ---------------- pass 1: row sums (KVBLK=128, K only) ----------------
    for (int kb0 = 0; kb0 < S_; kb0 += 128) {
#pragma unroll
        for (int j = 0; j < 4; ++j) {
            int u = t + (j << 8);
            int row = u >> 3, ch = u & 7;
            gload16(kp + rowbase + (size_t)(kb0 + row) * QKV_LD + ((ch ^ (row & 7)) << 3),
                    ar.ks1 + (w << 9) + (j << 11));
        }
        __syncthreads();
#pragma unroll
        for (int half = 0; half < 2; ++half) {
            int krow = half * 64 + wk * 32 + col;
            f32x16 s = ZERO16;
#pragma unroll
            for (int ci = 0; ci < 4; ++ci) {
                f16x8 kf = *reinterpret_cast<const f16x8*>(
                    &ar.ks1[krow * 64 + (((ci * 2 + hi) ^ (col & 7)) << 3)]);
                s = __builtin_amdgcn_mfma_f32_32x32x16_f16(qf[ci], kf, s, 0, 0, 0);
            }
            int kcol = kb0 + krow;
            const float* bl = bias_l + (kcol + 63 - (wq * 32 + hi4));
#pragma unroll
            for (int r = 0; r < 16; ++r) {
                const int cr = (r & 3) + 8 * (r >> 2);
                lsum[r] += __builtin_amdgcn_exp2f(s[r] + bl[-cr]);
            }
        }
        __syncthreads();
    }

    // reduce sums
#pragma unroll
    for (int off = 1; off < 32; off <<= 1) {
#pragma unroll
        for (int r = 0; r < 16; ++r) lsum[r] += __shfl_xor(lsum[r], off);
    }
    if (col == 0) {
#pragma unroll
        for (int r = 0; r < 16; ++r)
            red_l[wq * 32 + (r & 3) + 8 * (r >> 2) + hi4][wk] = lsum[r];
    }
    __syncthreads();
    if (t < 64) li_s[t] = 1.0f / (red_l[t][0] + red_l[t][1]);
    __syncthreads();
    float lreg[16];
#pragma unroll
    for (int r = 0; r < 16; ++r) lreg[r] = li_s[wq * 32 + (r & 3) + 8 * (r >> 2) + hi4];

    // ---------------- pass 2: recompute, write attn, PV ----------------
    f32x16 oacc = ZERO16;
    float* aout = attn_out + (((size_t)b * H_ + h) * S_ + q0) * S_;

    for (int kb0 = 0; kb0 < S_; kb0 += 64) {
#pragma unroll
        for (int j = 0; j < 2; ++j) {
            int u = t + (j << 8);
            int row = u >> 3, ch = u & 7;
            int sw = ((ch ^ (row & 7)) << 3);
            gload16(kp + rowbase + (size_t)(kb0 + row) * QKV_LD + sw,
                    ar.p2.ks + (w << 9) + (j << 11));
            gload16(vbase + (size_t)row * S_ + kb0 + sw,
                    ar.p2.vs + (w << 9) + (j << 11));
        }
        __syncthreads();
        int krow = wk * 32 + col;
        f32x16 s = ZERO16;
#pragma unroll
        for (int ci = 0; ci < 4; ++ci) {
            f16x8 kf = *reinterpret_cast<const f16x8*>(
                &ar.p2.ks[krow * 64 + (((ci * 2 + hi) ^ (col & 7)) << 3)]);
            s = __builtin_amdgcn_mfma_f32_32x32x16_f16(qf[ci], kf, s, 0, 0, 0);
        }
        int kcol = kb0 + krow;
        const float* bl = bias_l + (kcol + 63 - (wq * 32 + hi4));
#pragma unroll
        for (int r = 0; r < 16; ++r) {
            const int cr = (r & 3) + 8 * (r >> 2);
            int row = wq * 32 + cr + hi4;
            float p = __builtin_amdgcn_exp2f(s[r] + bl[-cr]) * lreg[r];
            __builtin_nontemporal_store(p, &aout[(size_t)row * S_ + kcol]);
            psh[row][wk * 32 + col] = (f16)p;
        }
        __syncthreads();
#pragma unroll
        for (int ci = 0; ci < 4; ++ci) {
            f16x8 pa = *reinterpret_cast<const f16x8*>(&psh[wq * 32 + col][ci * 16 + hi8]);
            f16x8 vf = *reinterpret_cast<const f16x8*>(
                &ar.p2.vs[krow * 64 + (((ci * 2 + hi) ^ (col & 7)) << 3)]);
            oacc = __builtin_amdgcn_mfma_f32_32x32x16_f16(pa, vf, oacc, 0, 0, 0);
        }
        __syncthreads();
    }

    // ctx write
    {
        f16* cbase = ctx_out + ((size_t)b * S_ + q0) * DMODEL + h * HS + wk * 32 + col;
#pragma unroll
        for (int r = 0; r < 16; ++r) {
            int row = wq * 32 + (r & 3) + 8 * (r >> 2) + hi4;
            cbase[(size_t)row * DMODEL] = (f16)oacc[r];
        }
    }
}

// ---------------- launch ----------------
extern "C" void kernel_launch(void* const* d_in, const int* in_sizes, int n_in,
                              void* d_out, int out_size, void* d_ws, size_t ws_size,
                              hipStream_t stream) {
    const float* x     = (const float*)d_in[0];
    const float* Wq    = (const float*)d_in[1];
    const float* Wk    = (const float*)d_in[2];
    const float* Wv    = (const float*)d_in[3];
    const float* Wo    = (const float*)d_in[4];
    const float* bw    = (const float*)d_in[5];
    const float* bfeat = (const float*)d_in[6];

    char* ws = (char*)d_ws;
    f16*   xb      = (f16*)(ws + 0);           // 4096x768      6,291,456 B (reused as vt after QKV GEMM)
    f16*   vt      = (f16*)(ws + 0);           // 24x64x2048    6,291,456 B
    f16*   qkv     = (f16*)(ws + 6291456);     // 4096x2304    18,874,368 B
    f16*   ctx     = (f16*)(ws + 25165824);    // 4096x768      6,291,456 B
    f16*   wqkv16  = (f16*)(ws + 31457280);    // 2304x768      3,538,944 B
    f16*   wo16    = (f16*)(ws + 34996224);    // 768x768       1,179,648 B
    float* biasTab = (float*)(ws + 36175872);  // 12x4095         196,560 B

    float* out0 = (float*)d_out;
    float* attn = out0 + (size_t)B_ * S_ * DMODEL;

    prep_kernel<<<5568, 256, 0, stream>>>(x, Wq, Wk, Wv, Wo, bw, bfeat,
                                          xb, wqkv16, wo16, biasTab);

    gemm_nt<f16><<<32 * 18, 256, 0, stream>>>(xb, wqkv16, qkv, 4096, QKV_LD, 768, 1.0f);

    vtrans_kernel<<<768, 256, 0, stream>>>(qkv, vt);

    attn_kernel<<<B_ * H_ * (S_ / 64), 256, 0, stream>>>(
        qkv + 0, qkv + 768, vt, biasTab, attn, ctx);

    gemm_nt<float><<<32 * 6, 256, 0, stream>>>(ctx, wo16, out0, 4096, DMODEL, 768, 1.0f);
}